// Round 2
// baseline (230.964 us; speedup 1.0000x reference)
//
#include <hip/hip_runtime.h>
#include <hip/hip_bf16.h>
#include <stdint.h>

#define NN 40000
#define EE 640000
#define HD 128
#define EDIM 32
#define DDIM 32
#define TDIM 128
#define ICH 320

#define TB 128  // edges per block (8 waves x 16)
#define KT 64   // k-chunk
#define PAD 8

typedef short  s16x8 __attribute__((ext_vector_type(8)));
typedef float  f32x4 __attribute__((ext_vector_type(4)));
typedef unsigned short u16;
typedef unsigned int   u32;

__device__ __forceinline__ u16 f2b(float f) {
  union { float f; u32 u; } x; x.f = f;
  u32 r = x.u + 0x7fffu + ((x.u >> 16) & 1u);   // RNE
  return (u16)(r >> 16);
}
__device__ __forceinline__ u32 pk2(float a, float b) {
  return (u32)f2b(a) | ((u32)f2b(b) << 16);
}

// ---- prep: h fp32 -> bf16 ----
__global__ void prep_h_kernel(const float* __restrict__ h, u16* __restrict__ wh) {
  int i = (blockIdx.x * 256 + threadIdx.x) * 4;
  if (i < NN * HD) {
    float4 v = *(const float4*)(h + i);
    *(uint2*)(wh + i) = make_uint2(pk2(v.x, v.y), pk2(v.z, v.w));
  }
}

// ---- prep: FiLM params t = silu(te) @ tW + tb  (256 outputs) ----
__global__ void prep_film_kernel(const float* __restrict__ te, const float* __restrict__ tW,
                                 const float* __restrict__ tb, float* __restrict__ film) {
  __shared__ float s[TDIM];
  int t = threadIdx.x;
  if (t < TDIM) { float v = te[t]; s[t] = v / (1.f + __expf(-v)); }
  __syncthreads();
  float acc = tb[t];
  #pragma unroll 8
  for (int k = 0; k < TDIM; ++k) acc += s[k] * tW[k * 256 + t];
  film[t] = acc;
}

// ---- prep: transpose W[K][128] -> Wt[128][K] bf16 ----
__global__ void prep_tr_kernel(const float* __restrict__ W, u16* __restrict__ Wt, int K) {
  int idx = blockIdx.x * 256 + threadIdx.x;
  if (idx < K * HD) {
    int k = idx >> 7, j = idx & 127;
    Wt[j * K + k] = f2b(W[idx]);
  }
}

// ---- out = pos (agg atomically added on top) ----
__global__ void copy_pos_kernel(const float* __restrict__ pos, float* __restrict__ out) {
  int i = blockIdx.x * 256 + threadIdx.x;
  if (i < NN * 3) out[i] = pos[i];
}

// ---- fused per-edge-tile kernel (swapped-operand MFMA: D[ch][edge]) ----
__global__ __launch_bounds__(512, 4) void edge_kernel(
    const float* __restrict__ pos,
    const float* __restrict__ edge_attr,
    const float* __restrict__ dist,
    const float* __restrict__ ib,
    const float* __restrict__ c1b,
    const float* __restrict__ c2w,
    const float* __restrict__ cn_scale,
    const int*   __restrict__ eidx,
    const u16*   __restrict__ wh,     // bf16 h [N][128]
    const u16*   __restrict__ wiWt,   // bf16 iW^T [128][320]
    const u16*   __restrict__ wc1Wt,  // bf16 c1W^T [128][128]
    const float* __restrict__ film,   // [256] shift|scale
    float*       __restrict__ out)
{
  __shared__ u16   sW[2][HD][KT + PAD];   // double-buffered weight chunk
  __shared__ u16   sX[TB][HD + PAD];      // modulated x (bf16), GEMM2 B^T source
  __shared__ float sIb[HD];
  __shared__ float sC1b[HD];
  __shared__ float sC2w[HD];
  __shared__ float sFilm[2 * HD];

  const int t    = threadIdx.x;
  const int lane = t & 63;
  const int wave = t >> 6;       // 0..7
  const int l15  = lane & 15;
  const int lg   = lane >> 4;    // 0..3
  const int e0   = blockIdx.x * TB;
  const int e    = e0 + wave * 16 + l15;   // this lane's edge

  if (t < HD) { sIb[t] = ib[t]; sC1b[t] = c1b[t]; sC2w[t] = c2w[t]; }
  if (t < 2 * HD) sFilm[t] = film[t];

  // per-lane edge node indices (kept live for epilogue)
  const int ri = eidx[e];
  const int ci = eidx[EE + e];

  // ---- prefetch all h-side B-fragments: hf[kt*2+ks] = src[k .. k+8) bf16 ----
  uint4 hf[8];
  {
    const u16* hr = wh + (size_t)ri * HD + lg * 8;
    const u16* hc = wh + (size_t)ci * HD + lg * 8;
    hf[0] = *(const uint4*)(hr);      hf[1] = *(const uint4*)(hr + 32);
    hf[2] = *(const uint4*)(hr + 64); hf[3] = *(const uint4*)(hr + 96);
    hf[4] = *(const uint4*)(hc);      hf[5] = *(const uint4*)(hc + 32);
    hf[6] = *(const uint4*)(hc + 64); hf[7] = *(const uint4*)(hc + 96);
  }

  // ---- weight-chunk staging: thread t -> row t>>2, 16-elem segment t&3 ----
  const int sj = t >> 2;
  const int ss = (t & 3) << 4;
#define STAGE(B, SRC, RS) {                                   \
    const u16* p_ = (SRC) + (size_t)sj * (RS) + ss;           \
    uint4 v0_ = *(const uint4*)(p_);                          \
    uint4 v1_ = *(const uint4*)(p_ + 8);                      \
    *(uint4*)&sW[B][sj][ss]     = v0_;                        \
    *(uint4*)&sW[B][sj][ss + 8] = v1_;                        \
  }

  f32x4 acc[8];
  #pragma unroll
  for (int n = 0; n < 8; ++n) acc[n] = (f32x4){0.f, 0.f, 0.f, 0.f};

  // MFMA one 64-k chunk: A = weight rows (channels), B = this lane's edge frags
#define MM1(B, F0, F1) {                                                        \
    s16x8 b0_ = *(const s16x8*)&(F0);                                           \
    s16x8 b1_ = *(const s16x8*)&(F1);                                           \
    _Pragma("unroll") for (int n = 0; n < 8; ++n) {                             \
      s16x8 a_ = *(const s16x8*)&sW[B][n * 16 + l15][lg * 8];                   \
      acc[n] = __builtin_amdgcn_mfma_f32_16x16x32_bf16(a_, b0_, acc[n], 0,0,0); \
    }                                                                           \
    _Pragma("unroll") for (int n = 0; n < 8; ++n) {                             \
      s16x8 a_ = *(const s16x8*)&sW[B][n * 16 + l15][32 + lg * 8];              \
      acc[n] = __builtin_amdgcn_mfma_f32_16x16x32_bf16(a_, b1_, acc[n], 0,0,0); \
    }                                                                           \
  }

  // ---------------- GEMM1: x^T = iW^T · h_input^T, K=320 in 5 chunks --------
  STAGE(0, wiWt + 0 * KT, ICH);
  __syncthreads();

  STAGE(1, wiWt + 1 * KT, ICH);  MM1(0, hf[0], hf[1]);  __syncthreads();
  STAGE(0, wiWt + 2 * KT, ICH);  MM1(1, hf[2], hf[3]);  __syncthreads();

  // issue attr/dist fp32 loads (converted two chunks later)
  float4 fa0, fa1, fd0, fd1;
  {
    const float* pa = edge_attr + (size_t)e * EDIM + lg * 8;
    const float* pd = dist      + (size_t)e * DDIM + lg * 8;
    fa0 = *(const float4*)(pa); fa1 = *(const float4*)(pa + 4);
    fd0 = *(const float4*)(pd); fd1 = *(const float4*)(pd + 4);
  }
  STAGE(1, wiWt + 3 * KT, ICH);  MM1(0, hf[4], hf[5]);  __syncthreads();
  STAGE(0, wiWt + 4 * KT, ICH);  MM1(1, hf[6], hf[7]);  __syncthreads();

  uint4 ef0, ef1;
  ef0.x = pk2(fa0.x, fa0.y); ef0.y = pk2(fa0.z, fa0.w);
  ef0.z = pk2(fa1.x, fa1.y); ef0.w = pk2(fa1.z, fa1.w);
  ef1.x = pk2(fd0.x, fd0.y); ef1.y = pk2(fd0.z, fd0.w);
  ef1.z = pk2(fd1.x, fd1.y); ef1.w = pk2(fd1.z, fd1.w);

  STAGE(1, wc1Wt + 0 * KT, HD);  MM1(0, ef0, ef1);      __syncthreads();

  // ---------- LayerNorm + FiLM: fully register-local per edge ----------
  // lane holds x[edge=e][ch = n*16 + lg*4 + r]
  float sum = 0.f, sq = 0.f;
  #pragma unroll
  for (int n = 0; n < 8; ++n)
    #pragma unroll
    for (int r = 0; r < 4; ++r) {
      float v = acc[n][r] + sIb[n * 16 + lg * 4 + r];
      sum += v; sq += v * v;
    }
  sum += __shfl_xor(sum, 16); sum += __shfl_xor(sum, 32);
  sq  += __shfl_xor(sq,  16); sq  += __shfl_xor(sq,  32);
  float mean = sum * (1.f / 128.f);
  float var  = sq  * (1.f / 128.f) - mean * mean;
  float rstd = rsqrtf(var + 1e-6f);

  #pragma unroll
  for (int n = 0; n < 8; ++n) {
    int cb = n * 16 + lg * 4;
    float x0 = (acc[n][0] + sIb[cb+0] - mean) * rstd * (1.f + sFilm[HD+cb+0]) + sFilm[cb+0];
    float x1 = (acc[n][1] + sIb[cb+1] - mean) * rstd * (1.f + sFilm[HD+cb+1]) + sFilm[cb+1];
    float x2 = (acc[n][2] + sIb[cb+2] - mean) * rstd * (1.f + sFilm[HD+cb+2]) + sFilm[cb+2];
    float x3 = (acc[n][3] + sIb[cb+3] - mean) * rstd * (1.f + sFilm[HD+cb+3]) + sFilm[cb+3];
    uint2 w; w.x = pk2(x0, x1); w.y = pk2(x2, x3);
    *(uint2*)&sX[wave * 16 + l15][cb] = w;
  }
  STAGE(0, wc1Wt + 1 * KT, HD);   // c1W chunk1 into buf0 (buf0 reads done at kt4 barrier)
  __syncthreads();                // sX + chunk1 visible; chunk0 already in buf1

  // ---------------- GEMM2: y^T = c1W^T · x^T, K=128 in 2 chunks -------------
  f32x4 acc2[8];
  #pragma unroll
  for (int n = 0; n < 8; ++n) acc2[n] = (f32x4){0.f, 0.f, 0.f, 0.f};

  #pragma unroll
  for (int kt2 = 0; kt2 < 2; ++kt2) {
    const int b = 1 - kt2;
    #pragma unroll
    for (int ks = 0; ks < 2; ++ks) {
      s16x8 xF = *(const s16x8*)&sX[wave * 16 + l15][kt2 * 64 + ks * 32 + lg * 8];
      #pragma unroll
      for (int n = 0; n < 8; ++n) {
        s16x8 aF = *(const s16x8*)&sW[b][n * 16 + l15][ks * 32 + lg * 8];
        acc2[n] = __builtin_amdgcn_mfma_f32_16x16x32_bf16(aF, xF, acc2[n], 0, 0, 0);
      }
    }
  }

  // ---------- silu -> dot(c2W) -> tanh -> per-lane scatter ----------
  float z = 0.f;
  #pragma unroll
  for (int n = 0; n < 8; ++n)
    #pragma unroll
    for (int r = 0; r < 4; ++r) {
      int ch  = n * 16 + lg * 4 + r;
      float y = acc2[n][r] + sC1b[ch];
      float sy = y / (1.f + __expf(-y));
      z += sy * sC2w[ch];
    }
  z += __shfl_xor(z, 16); z += __shfl_xor(z, 32);

  if (lg < 3) {   // lanes lg=0,1,2 handle dims x,y,z of edge e
    float inv = tanhf(z);
    float ax = pos[ri * 3 + 0] - pos[ci * 3 + 0];
    float ay = pos[ri * 3 + 1] - pos[ci * 3 + 1];
    float az = pos[ri * 3 + 2] - pos[ci * 3 + 2];
    float nrm = sqrtf(ax * ax + ay * ay + az * az);
    float sc  = cn_scale[0] * inv / fmaxf(nrm, 1e-8f);
    float d   = (lg == 0) ? ax : ((lg == 1) ? ay : az);
    atomicAdd(out + (size_t)ri * 3 + lg, d * sc);
  }
}

extern "C" void kernel_launch(void* const* d_in, const int* in_sizes, int n_in,
                              void* d_out, int out_size, void* d_ws, size_t ws_size,
                              hipStream_t stream) {
  const float* h         = (const float*)d_in[0];
  const float* pos       = (const float*)d_in[1];
  const float* edge_attr = (const float*)d_in[2];
  const float* dist      = (const float*)d_in[3];
  const float* te        = (const float*)d_in[4];
  const float* tW        = (const float*)d_in[5];
  const float* tb        = (const float*)d_in[6];
  const float* iW        = (const float*)d_in[7];
  const float* ib        = (const float*)d_in[8];
  const float* c1W       = (const float*)d_in[9];
  const float* c1b       = (const float*)d_in[10];
  const float* c2W       = (const float*)d_in[11];
  const float* cn        = (const float*)d_in[12];
  const int*   eidx      = (const int*)d_in[13];
  float* out = (float*)d_out;

  char* ws     = (char*)d_ws;
  u16*  wh     = (u16*)(ws);                 // 40000*128*2 = 10,240,000 B
  u16*  wiWt   = (u16*)(ws + 10240000);      // 128*320*2   =     81,920 B
  u16*  wc1Wt  = (u16*)(ws + 10321920);      // 128*128*2   =     32,768 B
  float* film  = (float*)(ws + 10354688);    // 256*4       =      1,024 B

  hipLaunchKernelGGL(prep_h_kernel,    dim3(5000), dim3(256), 0, stream, h, wh);
  hipLaunchKernelGGL(prep_film_kernel, dim3(1),    dim3(256), 0, stream, te, tW, tb, film);
  hipLaunchKernelGGL(prep_tr_kernel,   dim3(160),  dim3(256), 0, stream, iW, wiWt, ICH);
  hipLaunchKernelGGL(prep_tr_kernel,   dim3(64),   dim3(256), 0, stream, c1W, wc1Wt, HD);
  hipLaunchKernelGGL(copy_pos_kernel,  dim3(469),  dim3(256), 0, stream, pos, out);
  hipLaunchKernelGGL(edge_kernel,      dim3(EE / TB), dim3(512), 0, stream,
                     pos, edge_attr, dist, ib, c1b, c2W, cn, eidx,
                     wh, wiWt, wc1Wt, film, out);
}

// Round 4
// 138.768 us; speedup vs baseline: 1.6644x; 1.6644x over previous
//
#include <hip/hip_runtime.h>
#include <hip/hip_bf16.h>
#include <stdint.h>

#define NN 40000
#define EE 640000
#define HD 128
#define TDIM 128
#define TB 128

typedef short  s16x8 __attribute__((ext_vector_type(8)));
typedef float  f32x4 __attribute__((ext_vector_type(4)));
typedef unsigned short u16;
typedef unsigned int   u32;

__device__ __forceinline__ u32 cvtpk(float lo, float hi) {
  u32 r; asm("v_cvt_pk_bf16_f32 %0, %1, %2" : "=v"(r) : "v"(lo), "v"(hi)); return r;
}
__device__ __forceinline__ float b2f_lo(u32 w){ union{u32 u; float f;} x; x.u = w << 16; return x.f; }
__device__ __forceinline__ float b2f_hi(u32 w){ union{u32 u; float f;} x; x.u = w & 0xffff0000u; return x.f; }
__device__ __forceinline__ u16 f2b(float f) {
  union { float f; u32 u; } x; x.f = f;
  u32 r = x.u + 0x7fffu + ((x.u >> 16) & 1u);
  return (u16)(r >> 16);
}

// ---- FiLM params: film[0:128]=shift, film[128:256]=1+scale ----
__global__ void prep_film_kernel(const float* __restrict__ te, const float* __restrict__ tW,
                                 const float* __restrict__ tb, float* __restrict__ film) {
  __shared__ float s[TDIM];
  int t = threadIdx.x;
  if (t < TDIM) { float v = te[t]; s[t] = v * __builtin_amdgcn_rcpf(1.f + __expf(-v)); }
  __syncthreads();
  float acc = tb[t];
  #pragma unroll 8
  for (int k = 0; k < TDIM; ++k) acc = fmaf(s[k], tW[k * 256 + t], acc);
  film[t] = (t >= 128) ? (1.f + acc) : acc;
}

// ---- wPt[256][128]: wPt[c][k] = iW[(c>>7)*128 + k][c&127] ----
__global__ void prep_wpt_kernel(const float* __restrict__ iW, u16* __restrict__ wPt) {
  int idx = blockIdx.x * 256 + threadIdx.x;
  if (idx < 256 * 128) {
    int c = idx >> 7, k = idx & 127;
    wPt[idx] = f2b(iW[((c >> 7) * 128 + k) * HD + (c & 127)]);
  }
}

// ---- wadWt[128][64]: wadWt[c][k] = iW[256+k][c] ----
__global__ void prep_ad_kernel(const float* __restrict__ iW, u16* __restrict__ wadWt) {
  int idx = blockIdx.x * 256 + threadIdx.x;
  if (idx < 128 * 64) {
    int c = idx >> 6, k = idx & 63;
    wadWt[idx] = f2b(iW[(256 + k) * HD + c]);
  }
}

// ---- c1Wt[128][128]: c1Wt[c][k] = (1+scale[k]) * c1W[k][c] ----
__global__ void prep_c1w_kernel(const float* __restrict__ c1W, const float* __restrict__ film,
                                u16* __restrict__ c1Wt) {
  int idx = blockIdx.x * 256 + threadIdx.x;
  if (idx < 128 * 128) {
    int c = idx >> 7, k = idx & 127;
    c1Wt[idx] = f2b(film[128 + k] * c1W[k * HD + c]);
  }
}

// ---- biasp[c] = c1b[c] + sum_k shift[k] * c1W[k][c] ----
__global__ void prep_bias_kernel(const float* __restrict__ c1b, const float* __restrict__ film,
                                 const float* __restrict__ c1W, float* __restrict__ biasp) {
  int t = threadIdx.x;  // 0..127
  float acc = c1b[t];
  #pragma unroll 8
  for (int k = 0; k < 128; ++k) acc = fmaf(film[k], c1W[k * HD + t], acc);
  biasp[t] = acc;
}

// ---- P[node][256] bf16 in fragment-permuted order:
//      slot(ch<128)  = lg*32 + n*4 + r   where ch = n*16 + lg*4 + r
//      slot(ch>=128) = 128 + same for (ch-128)
//      value: P_r = h@iW_r + ib   |   P_c = h@iW_c ----
__global__ __launch_bounds__(256) void prep_P_kernel(const float* __restrict__ h,
                                                     const u16* __restrict__ wPt,
                                                     const float* __restrict__ ib,
                                                     u16* __restrict__ P) {
  __shared__ u16 sWp[256][136];
  __shared__ float sib[HD];
  int t = threadIdx.x;
  if (t < 128) sib[t] = ib[t];
  {
    const u16* src = wPt + t * 128;
    #pragma unroll
    for (int i = 0; i < 16; ++i)          // FIX: full 128-element row (was 8 -> half row garbage)
      *(uint4*)&sWp[t][i * 8] = *(const uint4*)(src + i * 8);
  }
  int wave = t >> 6, lane = t & 63, l15 = lane & 15, lg = lane >> 4;
  int node = blockIdx.x * 64 + wave * 16 + l15;
  uint4 hb[4];
  const float* hr = h + (size_t)node * HD + lg * 8;
  #pragma unroll
  for (int c = 0; c < 4; ++c) {
    float4 a = *(const float4*)(hr + c * 32);
    float4 b = *(const float4*)(hr + c * 32 + 4);
    hb[c].x = cvtpk(a.x, a.y); hb[c].y = cvtpk(a.z, a.w);
    hb[c].z = cvtpk(b.x, b.y); hb[c].w = cvtpk(b.z, b.w);
  }
  __syncthreads();
  f32x4 acc[16];
  #pragma unroll
  for (int n = 0; n < 16; ++n) acc[n] = (f32x4){0.f, 0.f, 0.f, 0.f};
  #pragma unroll
  for (int c = 0; c < 4; ++c) {
    s16x8 bF = *(const s16x8*)&hb[c];
    #pragma unroll
    for (int n = 0; n < 16; ++n) {
      s16x8 aF = *(const s16x8*)&sWp[n * 16 + l15][c * 32 + lg * 8];
      acc[n] = __builtin_amdgcn_mfma_f32_16x16x32_bf16(aF, bF, acc[n], 0, 0, 0);
    }
  }
  u16* dst = P + (size_t)node * 256;
  #pragma unroll
  for (int n = 0; n < 16; ++n) {
    int cb = n * 16 + lg * 4;  // semantic channel base (0..255)
    float a0 = acc[n][0], a1 = acc[n][1], a2 = acc[n][2], a3 = acc[n][3];
    if (n < 8) { a0 += sib[cb]; a1 += sib[cb + 1]; a2 += sib[cb + 2]; a3 += sib[cb + 3]; }
    int slot = (n < 8) ? (lg * 32 + n * 4) : (128 + lg * 32 + (n - 8) * 4);
    uint2 wv; wv.x = cvtpk(a0, a1); wv.y = cvtpk(a2, a3);
    *(uint2*)(dst + slot) = wv;
  }
}

// ---- out = pos ----
__global__ void copy_pos_kernel(const float* __restrict__ pos, float* __restrict__ out) {
  int i = blockIdx.x * 256 + threadIdx.x;
  if (i < NN * 3) out[i] = pos[i];
}

// ---- fused edge kernel: 3 barriers, 48 MFMA/wave ----
__global__ __launch_bounds__(512, 4) void edge_kernel(
    const float* __restrict__ pos,
    const float* __restrict__ edge_attr,
    const float* __restrict__ dist,
    const float* __restrict__ c2w,
    const float* __restrict__ cn_scale,
    const int*   __restrict__ eidx,
    const u16*   __restrict__ P,       // [N][256] bf16, fragment-permuted
    const u16*   __restrict__ wadWt,   // [128][64]
    const u16*   __restrict__ c1Wt,    // [128][128] (FiLM-scaled)
    const float* __restrict__ biasp,   // [128] (c1b + shift@c1W)
    float*       __restrict__ out)
{
  __shared__ u16   sWc[HD * HD];   // 32 KB: c1Wt, swizzled
  __shared__ u16   sUni[HD * HD];  // 32 KB: phase1 = wadWt (16 KB), phase2 = sX
  __shared__ float sC1b[HD];
  __shared__ float sC2w[HD];

  const int t    = threadIdx.x;
  const int lane = t & 63;
  const int wave = t >> 6;
  const int l15  = lane & 15;
  const int lg   = lane >> 4;
  const int e    = blockIdx.x * TB + wave * 16 + l15;

  if (t < HD) { sC1b[t] = biasp[t]; sC2w[t] = c2w[t]; }

  const int ri = eidx[e];
  const int ci = eidx[EE + e];
  const float cns = cn_scale[0];

  // ---- early gathers: P rows (64B contiguous per lane), attr/dist, pos ----
  uint4 pra[4], pca[4];
  {
    const u16* prp = P + (size_t)ri * 256 + lg * 32;
    const u16* pcp = P + (size_t)ci * 256 + 128 + lg * 32;
    #pragma unroll
    for (int i = 0; i < 4; ++i) { pra[i] = *(const uint4*)(prp + i * 8); }
    #pragma unroll
    for (int i = 0; i < 4; ++i) { pca[i] = *(const uint4*)(pcp + i * 8); }
  }
  float4 fa0, fa1, fd0, fd1;
  {
    const float* pa = edge_attr + (size_t)e * 32 + lg * 8;
    const float* pd = dist      + (size_t)e * 32 + lg * 8;
    fa0 = *(const float4*)(pa); fa1 = *(const float4*)(pa + 4);
    fd0 = *(const float4*)(pd); fd1 = *(const float4*)(pd + 4);
  }
  float p0x = pos[ri * 3 + 0], p0y = pos[ri * 3 + 1], p0z = pos[ri * 3 + 2];
  float p1x = pos[ci * 3 + 0], p1y = pos[ci * 3 + 1], p1z = pos[ci * 3 + 2];

  // ---- stage weights (linear global read, XOR-swizzled LDS write) ----
  {
    int o = t * 32;                      // sWq region: 512 thr * 32B = 16 KB
    int sw = ((o >> 7) & 7) << 4;
    uint4 v0 = *(const uint4*)(wadWt + (o >> 1));
    uint4 v1 = *(const uint4*)(wadWt + (o >> 1) + 8);
    *(uint4*)((char*)sUni + (o ^ sw))        = v0;
    *(uint4*)((char*)sUni + ((o + 16) ^ sw)) = v1;
  }
  {
    int ob = t * 64;                     // sWc: 512 thr * 64B = 32 KB
    int sw = ((ob >> 8) & 7) << 4;
    #pragma unroll
    for (int i = 0; i < 4; ++i) {
      int o = ob + i * 16;
      uint4 v = *(const uint4*)(c1Wt + (o >> 1));
      *(uint4*)((char*)sWc + (o ^ sw)) = v;
    }
  }

  // ---- attr/dist -> bf16 fragments (k 0..31 = attr, 32..63 = dist) ----
  uint4 ef0, ef1;
  ef0.x = cvtpk(fa0.x, fa0.y); ef0.y = cvtpk(fa0.z, fa0.w);
  ef0.z = cvtpk(fa1.x, fa1.y); ef0.w = cvtpk(fa1.z, fa1.w);
  ef1.x = cvtpk(fd0.x, fd0.y); ef1.y = cvtpk(fd0.z, fd0.w);
  ef1.z = cvtpk(fd1.x, fd1.y); ef1.w = cvtpk(fd1.z, fd1.w);

  __syncthreads();   // bar1: staging + consts visible

  // ---- Q = [attr|dist] @ iW_ad : 16 MFMAs ----
  f32x4 acc[8];
  #pragma unroll
  for (int n = 0; n < 8; ++n) acc[n] = (f32x4){0.f, 0.f, 0.f, 0.f};
  #pragma unroll
  for (int ks = 0; ks < 2; ++ks) {
    s16x8 bF = (ks == 0) ? *(const s16x8*)&ef0 : *(const s16x8*)&ef1;
    #pragma unroll
    for (int n = 0; n < 8; ++n) {
      int row = n * 16 + l15;
      int o = (row * 128 + ks * 64 + lg * 16) ^ ((row & 7) << 4);
      s16x8 aF = *(const s16x8*)((const char*)sUni + o);
      acc[n] = __builtin_amdgcn_mfma_f32_16x16x32_bf16(aF, bF, acc[n], 0, 0, 0);
    }
  }

  // ---- x = Q + P_r[ri] + P_c[ci]; LayerNorm stats in registers ----
  float x[8][4];
  float sum = 0.f, sq = 0.f;
  #pragma unroll
  for (int i = 0; i < 4; ++i) {
    u32 w0 = pra[i].x, w1 = pra[i].y, w2 = pra[i].z, w3 = pra[i].w;
    u32 u0 = pca[i].x, u1 = pca[i].y, u2 = pca[i].z, u3 = pca[i].w;
    float v0 = acc[2*i][0] + b2f_lo(w0) + b2f_lo(u0);
    float v1 = acc[2*i][1] + b2f_hi(w0) + b2f_hi(u0);
    float v2 = acc[2*i][2] + b2f_lo(w1) + b2f_lo(u1);
    float v3 = acc[2*i][3] + b2f_hi(w1) + b2f_hi(u1);
    float v4 = acc[2*i+1][0] + b2f_lo(w2) + b2f_lo(u2);
    float v5 = acc[2*i+1][1] + b2f_hi(w2) + b2f_hi(u2);
    float v6 = acc[2*i+1][2] + b2f_lo(w3) + b2f_lo(u3);
    float v7 = acc[2*i+1][3] + b2f_hi(w3) + b2f_hi(u3);
    x[2*i][0]=v0; x[2*i][1]=v1; x[2*i][2]=v2; x[2*i][3]=v3;
    x[2*i+1][0]=v4; x[2*i+1][1]=v5; x[2*i+1][2]=v6; x[2*i+1][3]=v7;
    sum += v0+v1+v2+v3+v4+v5+v6+v7;
    sq = fmaf(v0,v0,sq); sq = fmaf(v1,v1,sq); sq = fmaf(v2,v2,sq); sq = fmaf(v3,v3,sq);
    sq = fmaf(v4,v4,sq); sq = fmaf(v5,v5,sq); sq = fmaf(v6,v6,sq); sq = fmaf(v7,v7,sq);
  }
  sum += __shfl_xor(sum, 16); sum += __shfl_xor(sum, 32);
  sq  += __shfl_xor(sq,  16); sq  += __shfl_xor(sq,  32);
  float mean = sum * (1.f / 128.f);
  float var  = sq  * (1.f / 128.f) - mean * mean;
  float A = rsqrtf(var + 1e-6f);
  float B = -mean * A;

  __syncthreads();   // bar2: all waves done reading sUni(Q weights)

  // ---- t = (x-mean)*rstd -> bf16 -> sX (FiLM folded into c1Wt/biasp) ----
  const int xrow = wave * 16 + l15;
  const int xsw  = (xrow & 7) << 4;
  #pragma unroll
  for (int n = 0; n < 8; ++n) {
    float y0 = fmaf(x[n][0], A, B);
    float y1 = fmaf(x[n][1], A, B);
    float y2 = fmaf(x[n][2], A, B);
    float y3 = fmaf(x[n][3], A, B);
    uint2 wv; wv.x = cvtpk(y0, y1); wv.y = cvtpk(y2, y3);
    int o = (xrow * 256 + n * 32 + lg * 8) ^ xsw;
    *(uint2*)((char*)sUni + o) = wv;
  }
  __syncthreads();   // bar3: sX visible

  // ---- GEMM2: y^T = c1Wt . t^T : 32 MFMAs ----
  f32x4 acc2[8];
  #pragma unroll
  for (int n = 0; n < 8; ++n) acc2[n] = (f32x4){0.f, 0.f, 0.f, 0.f};
  #pragma unroll
  for (int kq = 0; kq < 4; ++kq) {
    int ko = kq * 64 + lg * 16;
    int xo = (xrow * 256 + ko) ^ xsw;
    s16x8 xF = *(const s16x8*)((const char*)sUni + xo);
    #pragma unroll
    for (int n = 0; n < 8; ++n) {
      int row = n * 16 + l15;
      int o = (row * 256 + ko) ^ ((row & 7) << 4);
      s16x8 aF = *(const s16x8*)((const char*)sWc + o);
      acc2[n] = __builtin_amdgcn_mfma_f32_16x16x32_bf16(aF, xF, acc2[n], 0, 0, 0);
    }
  }

  // ---- silu -> dot(c2W) -> tanh -> scatter ----
  float z = 0.f;
  #pragma unroll
  for (int n = 0; n < 8; ++n) {
    int cb = n * 16 + lg * 4;
    f32x4 cb4 = *(const f32x4*)&sC1b[cb];
    f32x4 cw4 = *(const f32x4*)&sC2w[cb];
    #pragma unroll
    for (int r = 0; r < 4; ++r) {
      float y = acc2[n][r] + cb4[r];
      float s = y * __builtin_amdgcn_rcpf(1.f + __expf(-y));
      z = fmaf(s, cw4[r], z);
    }
  }
  z += __shfl_xor(z, 16); z += __shfl_xor(z, 32);

  if (lg < 3) {
    float zc = fminf(fmaxf(z, -15.f), 15.f);
    float ez = __expf(2.f * zc);
    float inv = (ez - 1.f) * __builtin_amdgcn_rcpf(ez + 1.f);
    float dx = p0x - p1x, dy = p0y - p1y, dz = p0z - p1z;
    float nrm = sqrtf(fmaf(dx, dx, fmaf(dy, dy, dz * dz)));
    float sc  = cns * inv * __builtin_amdgcn_rcpf(fmaxf(nrm, 1e-8f));
    float d   = (lg == 0) ? dx : ((lg == 1) ? dy : dz);
    atomicAdd(out + (size_t)ri * 3 + lg, d * sc);
  }
}

extern "C" void kernel_launch(void* const* d_in, const int* in_sizes, int n_in,
                              void* d_out, int out_size, void* d_ws, size_t ws_size,
                              hipStream_t stream) {
  const float* h         = (const float*)d_in[0];
  const float* pos       = (const float*)d_in[1];
  const float* edge_attr = (const float*)d_in[2];
  const float* dist      = (const float*)d_in[3];
  const float* te        = (const float*)d_in[4];
  const float* tW        = (const float*)d_in[5];
  const float* tb        = (const float*)d_in[6];
  const float* iW        = (const float*)d_in[7];
  const float* ib        = (const float*)d_in[8];
  const float* c1W       = (const float*)d_in[9];
  const float* c1b       = (const float*)d_in[10];
  const float* c2W       = (const float*)d_in[11];
  const float* cn        = (const float*)d_in[12];
  const int*   eidx      = (const int*)d_in[13];
  float* out = (float*)d_out;

  char* ws = (char*)d_ws;
  u16*   P      = (u16*)(ws);                    // 40000*256*2 = 20,480,000 B
  u16*   wPt    = (u16*)(ws + 20480000);         // 65,536 B
  u16*   wadWt  = (u16*)(ws + 20545536);         // 16,384 B
  u16*   c1Wt   = (u16*)(ws + 20561920);         // 32,768 B
  float* film   = (float*)(ws + 20594688);       // 1,024 B
  float* biasp  = (float*)(ws + 20595712);       // 512 B

  hipLaunchKernelGGL(prep_film_kernel, dim3(1),   dim3(256), 0, stream, te, tW, tb, film);
  hipLaunchKernelGGL(prep_wpt_kernel,  dim3(128), dim3(256), 0, stream, iW, wPt);
  hipLaunchKernelGGL(prep_ad_kernel,   dim3(32),  dim3(256), 0, stream, iW, wadWt);
  hipLaunchKernelGGL(prep_c1w_kernel,  dim3(64),  dim3(256), 0, stream, c1W, film, c1Wt);
  hipLaunchKernelGGL(prep_bias_kernel, dim3(1),   dim3(128), 0, stream, c1b, film, c1W, biasp);
  hipLaunchKernelGGL(prep_P_kernel,    dim3(625), dim3(256), 0, stream, h, wPt, ib, P);
  hipLaunchKernelGGL(copy_pos_kernel,  dim3(469), dim3(256), 0, stream, pos, out);
  hipLaunchKernelGGL(edge_kernel,      dim3(EE / TB), dim3(512), 0, stream,
                     pos, edge_attr, dist, c2W, cn, eidx,
                     P, wadWt, c1Wt, biasp, out);
}

// Round 5
// 132.173 us; speedup vs baseline: 1.7474x; 1.0499x over previous
//
#include <hip/hip_runtime.h>
#include <hip/hip_bf16.h>
#include <stdint.h>

#define NN 40000
#define EE 640000
#define HD 128
#define TDIM 128
#define TB 128

typedef short  s16x8 __attribute__((ext_vector_type(8)));
typedef float  f32x4 __attribute__((ext_vector_type(4)));
typedef unsigned int u32x4 __attribute__((ext_vector_type(4)));
typedef unsigned short u16;
typedef unsigned int   u32;

__device__ __forceinline__ u32 cvtpk(float lo, float hi) {
  u32 r; asm("v_cvt_pk_bf16_f32 %0, %1, %2" : "=v"(r) : "v"(lo), "v"(hi)); return r;
}
__device__ __forceinline__ float b2f_lo(u32 w){ union{u32 u; float f;} x; x.u = w << 16; return x.f; }
__device__ __forceinline__ float b2f_hi(u32 w){ union{u32 u; float f;} x; x.u = w & 0xffff0000u; return x.f; }
__device__ __forceinline__ u16 f2b(float f) {
  union { float f; u32 u; } x; x.f = f;
  u32 r = x.u + 0x7fffu + ((x.u >> 16) & 1u);
  return (u16)(r >> 16);
}

// ---- FiLM params: film[0:128]=shift, film[128:256]=1+scale ----
__global__ void prep_film_kernel(const float* __restrict__ te, const float* __restrict__ tW,
                                 const float* __restrict__ tb, float* __restrict__ film) {
  __shared__ float s[TDIM];
  int t = threadIdx.x;
  if (t < TDIM) { float v = te[t]; s[t] = v * __builtin_amdgcn_rcpf(1.f + __expf(-v)); }
  __syncthreads();
  float acc = tb[t];
  #pragma unroll 8
  for (int k = 0; k < TDIM; ++k) acc = fmaf(s[k], tW[k * 256 + t], acc);
  film[t] = (t >= 128) ? (1.f + acc) : acc;
}

// ---- wPt[256][128]: wPt[c][k] = iW[(c>>7)*128 + k][c&127] ----
__global__ void prep_wpt_kernel(const float* __restrict__ iW, u16* __restrict__ wPt) {
  int idx = blockIdx.x * 256 + threadIdx.x;
  if (idx < 256 * 128) {
    int c = idx >> 7, k = idx & 127;
    wPt[idx] = f2b(iW[((c >> 7) * 128 + k) * HD + (c & 127)]);
  }
}

// ---- wadWt[128][64]: wadWt[c][k] = iW[256+k][c] ----
__global__ void prep_ad_kernel(const float* __restrict__ iW, u16* __restrict__ wadWt) {
  int idx = blockIdx.x * 256 + threadIdx.x;
  if (idx < 128 * 64) {
    int c = idx >> 6, k = idx & 63;
    wadWt[idx] = f2b(iW[(256 + k) * HD + c]);
  }
}

// ---- c1Wt[128][128], K-axis PERMUTED to match LN register layout:
//      slot p (kq=p>>5, lg=(p>>3)&3, j=p&7) holds channel
//      ch = (2*kq + (j>>2))*16 + lg*4 + (j&3), scaled by (1+scale[ch]) ----
__global__ void prep_c1w_kernel(const float* __restrict__ c1W, const float* __restrict__ film,
                                u16* __restrict__ c1Wt) {
  int idx = blockIdx.x * 256 + threadIdx.x;
  if (idx < 128 * 128) {
    int c = idx >> 7, p = idx & 127;
    int kq = p >> 5, lg = (p >> 3) & 3, j = p & 7;
    int ch = (kq * 2 + (j >> 2)) * 16 + lg * 4 + (j & 3);
    c1Wt[idx] = f2b(film[128 + ch] * c1W[ch * HD + c]);
  }
}

// ---- biasp[c] = c1b[c] + sum_k shift[k] * c1W[k][c] ----
__global__ void prep_bias_kernel(const float* __restrict__ c1b, const float* __restrict__ film,
                                 const float* __restrict__ c1W, float* __restrict__ biasp) {
  int t = threadIdx.x;  // 0..127
  float acc = c1b[t];
  #pragma unroll 8
  for (int k = 0; k < 128; ++k) acc = fmaf(film[k], c1W[k * HD + t], acc);
  biasp[t] = acc;
}

// ---- P[node][256] bf16 in fragment-permuted order (see R3 notes) ----
__global__ __launch_bounds__(256) void prep_P_kernel(const float* __restrict__ h,
                                                     const u16* __restrict__ wPt,
                                                     const float* __restrict__ ib,
                                                     u16* __restrict__ P) {
  __shared__ u16 sWp[256][136];
  __shared__ float sib[HD];
  int t = threadIdx.x;
  if (t < 128) sib[t] = ib[t];
  {
    const u16* src = wPt + t * 128;
    #pragma unroll
    for (int i = 0; i < 16; ++i)
      *(uint4*)&sWp[t][i * 8] = *(const uint4*)(src + i * 8);
  }
  int wave = t >> 6, lane = t & 63, l15 = lane & 15, lg = lane >> 4;
  int node = blockIdx.x * 64 + wave * 16 + l15;
  uint4 hb[4];
  const float* hr = h + (size_t)node * HD + lg * 8;
  #pragma unroll
  for (int c = 0; c < 4; ++c) {
    float4 a = *(const float4*)(hr + c * 32);
    float4 b = *(const float4*)(hr + c * 32 + 4);
    hb[c].x = cvtpk(a.x, a.y); hb[c].y = cvtpk(a.z, a.w);
    hb[c].z = cvtpk(b.x, b.y); hb[c].w = cvtpk(b.z, b.w);
  }
  __syncthreads();
  f32x4 acc[16];
  #pragma unroll
  for (int n = 0; n < 16; ++n) acc[n] = (f32x4){0.f, 0.f, 0.f, 0.f};
  #pragma unroll
  for (int c = 0; c < 4; ++c) {
    s16x8 bF = *(const s16x8*)&hb[c];
    #pragma unroll
    for (int n = 0; n < 16; ++n) {
      s16x8 aF = *(const s16x8*)&sWp[n * 16 + l15][c * 32 + lg * 8];
      acc[n] = __builtin_amdgcn_mfma_f32_16x16x32_bf16(aF, bF, acc[n], 0, 0, 0);
    }
  }
  u16* dst = P + (size_t)node * 256;
  #pragma unroll
  for (int n = 0; n < 16; ++n) {
    int cb = n * 16 + lg * 4;
    float a0 = acc[n][0], a1 = acc[n][1], a2 = acc[n][2], a3 = acc[n][3];
    if (n < 8) { a0 += sib[cb]; a1 += sib[cb + 1]; a2 += sib[cb + 2]; a3 += sib[cb + 3]; }
    int slot = (n < 8) ? (lg * 32 + n * 4) : (128 + lg * 32 + (n - 8) * 4);
    uint2 wv; wv.x = cvtpk(a0, a1); wv.y = cvtpk(a2, a3);
    *(uint2*)(dst + slot) = wv;
  }
}

// ---- out = pos ----
__global__ void copy_pos_kernel(const float* __restrict__ pos, float* __restrict__ out) {
  int i = blockIdx.x * 256 + threadIdx.x;
  if (i < NN * 3) out[i] = pos[i];
}

// ---- fused edge kernel: ONE barrier, GEMM2 B-operand fully in registers ----
__global__ __launch_bounds__(512) void edge_kernel(
    const float* __restrict__ pos,
    const float* __restrict__ edge_attr,
    const float* __restrict__ dist,
    const float* __restrict__ c2w,
    const float* __restrict__ cn_scale,
    const int*   __restrict__ eidx,
    const u16*   __restrict__ P,       // [N][256] bf16, fragment-permuted
    const u16*   __restrict__ wadWt,   // [128][64]
    const u16*   __restrict__ c1Wt,    // [128][128] FiLM-scaled, k-permuted
    const float* __restrict__ biasp,   // [128] (c1b + shift@c1W)
    float*       __restrict__ out)
{
  __shared__ u16   sWc[HD * HD];      // 32 KB: c1Wt (k-permuted), swizzled
  __shared__ u16   sWq[HD * 64];      // 16 KB: wadWt, swizzled
  __shared__ float sC1b[HD];
  __shared__ float sC2w[HD];

  const int t    = threadIdx.x;
  const int lane = t & 63;
  const int wave = t >> 6;
  const int l15  = lane & 15;
  const int lg   = lane >> 4;
  const int e    = blockIdx.x * TB + wave * 16 + l15;

  if (t < HD) { sC1b[t] = biasp[t]; sC2w[t] = c2w[t]; }

  const int ri = eidx[e];
  const int ci = eidx[EE + e];
  const float cns = cn_scale[0];

  // ---- early gathers: P rows (64B contiguous per lane), attr/dist, pos ----
  uint4 pra[4], pca[4];
  {
    const u16* prp = P + (size_t)ri * 256 + lg * 32;
    const u16* pcp = P + (size_t)ci * 256 + 128 + lg * 32;
    #pragma unroll
    for (int i = 0; i < 4; ++i) { pra[i] = *(const uint4*)(prp + i * 8); }
    #pragma unroll
    for (int i = 0; i < 4; ++i) { pca[i] = *(const uint4*)(pcp + i * 8); }
  }
  float4 fa0, fa1, fd0, fd1;
  {
    const float* pa = edge_attr + (size_t)e * 32 + lg * 8;
    const float* pd = dist      + (size_t)e * 32 + lg * 8;
    fa0 = *(const float4*)(pa); fa1 = *(const float4*)(pa + 4);
    fd0 = *(const float4*)(pd); fd1 = *(const float4*)(pd + 4);
  }
  float p0x = pos[ri * 3 + 0], p0y = pos[ri * 3 + 1], p0z = pos[ri * 3 + 2];
  float p1x = pos[ci * 3 + 0], p1y = pos[ci * 3 + 1], p1z = pos[ci * 3 + 2];

  // ---- stage weights (linear global read, XOR-swizzled LDS write) ----
  {
    int o = t * 32;                      // sWq: 512 thr * 32B = 16 KB
    int sw = ((o >> 7) & 7) << 4;
    uint4 v0 = *(const uint4*)(wadWt + (o >> 1));
    uint4 v1 = *(const uint4*)(wadWt + (o >> 1) + 8);
    *(uint4*)((char*)sWq + (o ^ sw))        = v0;
    *(uint4*)((char*)sWq + ((o + 16) ^ sw)) = v1;
  }
  {
    int ob = t * 64;                     // sWc: 512 thr * 64B = 32 KB
    int sw = ((ob >> 8) & 7) << 4;
    #pragma unroll
    for (int i = 0; i < 4; ++i) {
      int o = ob + i * 16;
      uint4 v = *(const uint4*)(c1Wt + (o >> 1));
      *(uint4*)((char*)sWc + (o ^ sw)) = v;
    }
  }

  // ---- attr/dist -> bf16 fragments (k 0..31 = attr, 32..63 = dist) ----
  uint4 ef0, ef1;
  ef0.x = cvtpk(fa0.x, fa0.y); ef0.y = cvtpk(fa0.z, fa0.w);
  ef0.z = cvtpk(fa1.x, fa1.y); ef0.w = cvtpk(fa1.z, fa1.w);
  ef1.x = cvtpk(fd0.x, fd0.y); ef1.y = cvtpk(fd0.z, fd0.w);
  ef1.z = cvtpk(fd1.x, fd1.y); ef1.w = cvtpk(fd1.z, fd1.w);

  __syncthreads();   // the ONLY barrier: staging + consts visible

  // ---- Q = [attr|dist] @ iW_ad : 16 MFMAs ----
  f32x4 acc[8];
  #pragma unroll
  for (int n = 0; n < 8; ++n) acc[n] = (f32x4){0.f, 0.f, 0.f, 0.f};
  #pragma unroll
  for (int ks = 0; ks < 2; ++ks) {
    s16x8 bF = (ks == 0) ? *(const s16x8*)&ef0 : *(const s16x8*)&ef1;
    #pragma unroll
    for (int n = 0; n < 8; ++n) {
      int row = n * 16 + l15;
      int o = (row * 128 + ks * 64 + lg * 16) ^ ((row & 7) << 4);
      s16x8 aF = *(const s16x8*)((const char*)sWq + o);
      acc[n] = __builtin_amdgcn_mfma_f32_16x16x32_bf16(aF, bF, acc[n], 0, 0, 0);
    }
  }

  // ---- x = Q + P_r[ri] + P_c[ci]; LayerNorm stats in registers ----
  float x[8][4];
  float sum = 0.f, sq = 0.f;
  #pragma unroll
  for (int i = 0; i < 4; ++i) {
    u32 w0 = pra[i].x, w1 = pra[i].y, w2 = pra[i].z, w3 = pra[i].w;
    u32 u0 = pca[i].x, u1 = pca[i].y, u2 = pca[i].z, u3 = pca[i].w;
    float v0 = acc[2*i][0] + b2f_lo(w0) + b2f_lo(u0);
    float v1 = acc[2*i][1] + b2f_hi(w0) + b2f_hi(u0);
    float v2 = acc[2*i][2] + b2f_lo(w1) + b2f_lo(u1);
    float v3 = acc[2*i][3] + b2f_hi(w1) + b2f_hi(u1);
    float v4 = acc[2*i+1][0] + b2f_lo(w2) + b2f_lo(u2);
    float v5 = acc[2*i+1][1] + b2f_hi(w2) + b2f_hi(u2);
    float v6 = acc[2*i+1][2] + b2f_lo(w3) + b2f_lo(u3);
    float v7 = acc[2*i+1][3] + b2f_hi(w3) + b2f_hi(u3);
    x[2*i][0]=v0; x[2*i][1]=v1; x[2*i][2]=v2; x[2*i][3]=v3;
    x[2*i+1][0]=v4; x[2*i+1][1]=v5; x[2*i+1][2]=v6; x[2*i+1][3]=v7;
    sum += v0+v1+v2+v3+v4+v5+v6+v7;
    sq = fmaf(v0,v0,sq); sq = fmaf(v1,v1,sq); sq = fmaf(v2,v2,sq); sq = fmaf(v3,v3,sq);
    sq = fmaf(v4,v4,sq); sq = fmaf(v5,v5,sq); sq = fmaf(v6,v6,sq); sq = fmaf(v7,v7,sq);
  }
  sum += __shfl_xor(sum, 16); sum += __shfl_xor(sum, 32);
  sq  += __shfl_xor(sq,  16); sq  += __shfl_xor(sq,  32);
  float mean = sum * (1.f / 128.f);
  float var  = sq  * (1.f / 128.f) - mean * mean;
  float A = rsqrtf(var + 1e-6f);
  float B = -mean * A;

  // ---- LN -> bf16 pairs, kept in registers (GEMM2 B-operand) ----
  // xb.w[4*kq + i] are exactly the 4 dwords of the kq-th B-fragment
  union { uint2 u2[8]; u32 w[16]; } xb;
  #pragma unroll
  for (int n = 0; n < 8; ++n) {
    float y0 = fmaf(x[n][0], A, B);
    float y1 = fmaf(x[n][1], A, B);
    float y2 = fmaf(x[n][2], A, B);
    float y3 = fmaf(x[n][3], A, B);
    xb.u2[n].x = cvtpk(y0, y1);
    xb.u2[n].y = cvtpk(y2, y3);
  }

  // ---- GEMM2: y^T = c1Wt(k-perm) . t^T : 32 MFMAs, B from registers ----
  f32x4 acc2[8];
  #pragma unroll
  for (int n = 0; n < 8; ++n) acc2[n] = (f32x4){0.f, 0.f, 0.f, 0.f};
  #pragma unroll
  for (int kq = 0; kq < 4; ++kq) {
    u32x4 xw = { xb.w[4*kq], xb.w[4*kq+1], xb.w[4*kq+2], xb.w[4*kq+3] };
    s16x8 xF = __builtin_bit_cast(s16x8, xw);
    int ko = kq * 64 + lg * 16;
    #pragma unroll
    for (int n = 0; n < 8; ++n) {
      int row = n * 16 + l15;
      int o = (row * 256 + ko) ^ ((row & 7) << 4);
      s16x8 aF = *(const s16x8*)((const char*)sWc + o);
      acc2[n] = __builtin_amdgcn_mfma_f32_16x16x32_bf16(aF, xF, acc2[n], 0, 0, 0);
    }
  }

  // ---- silu -> dot(c2W) -> tanh -> scatter ----
  float z = 0.f;
  #pragma unroll
  for (int n = 0; n < 8; ++n) {
    int cb = n * 16 + lg * 4;
    f32x4 cb4 = *(const f32x4*)&sC1b[cb];
    f32x4 cw4 = *(const f32x4*)&sC2w[cb];
    #pragma unroll
    for (int r = 0; r < 4; ++r) {
      float y = acc2[n][r] + cb4[r];
      float s = y * __builtin_amdgcn_rcpf(1.f + __expf(-y));
      z = fmaf(s, cw4[r], z);
    }
  }
  z += __shfl_xor(z, 16); z += __shfl_xor(z, 32);

  if (lg < 3) {
    float zc = fminf(fmaxf(z, -15.f), 15.f);
    float ez = __expf(2.f * zc);
    float inv = (ez - 1.f) * __builtin_amdgcn_rcpf(ez + 1.f);
    float dx = p0x - p1x, dy = p0y - p1y, dz = p0z - p1z;
    float nrm = sqrtf(fmaf(dx, dx, fmaf(dy, dy, dz * dz)));
    float sc  = cns * inv * __builtin_amdgcn_rcpf(fmaxf(nrm, 1e-8f));
    float d   = (lg == 0) ? dx : ((lg == 1) ? dy : dz);
    atomicAdd(out + (size_t)ri * 3 + lg, d * sc);
  }
}

extern "C" void kernel_launch(void* const* d_in, const int* in_sizes, int n_in,
                              void* d_out, int out_size, void* d_ws, size_t ws_size,
                              hipStream_t stream) {
  const float* h         = (const float*)d_in[0];
  const float* pos       = (const float*)d_in[1];
  const float* edge_attr = (const float*)d_in[2];
  const float* dist      = (const float*)d_in[3];
  const float* te        = (const float*)d_in[4];
  const float* tW        = (const float*)d_in[5];
  const float* tb        = (const float*)d_in[6];
  const float* iW        = (const float*)d_in[7];
  const float* ib        = (const float*)d_in[8];
  const float* c1W       = (const float*)d_in[9];
  const float* c1b       = (const float*)d_in[10];
  const float* c2W       = (const float*)d_in[11];
  const float* cn        = (const float*)d_in[12];
  const int*   eidx      = (const int*)d_in[13];
  float* out = (float*)d_out;

  char* ws = (char*)d_ws;
  u16*   P      = (u16*)(ws);                    // 40000*256*2 = 20,480,000 B
  u16*   wPt    = (u16*)(ws + 20480000);         // 65,536 B
  u16*   wadWt  = (u16*)(ws + 20545536);         // 16,384 B
  u16*   c1Wt   = (u16*)(ws + 20561920);         // 32,768 B
  float* film   = (float*)(ws + 20594688);       // 1,024 B
  float* biasp  = (float*)(ws + 20595712);       // 512 B

  hipLaunchKernelGGL(prep_film_kernel, dim3(1),   dim3(256), 0, stream, te, tW, tb, film);
  hipLaunchKernelGGL(prep_wpt_kernel,  dim3(128), dim3(256), 0, stream, iW, wPt);
  hipLaunchKernelGGL(prep_ad_kernel,   dim3(32),  dim3(256), 0, stream, iW, wadWt);
  hipLaunchKernelGGL(prep_c1w_kernel,  dim3(64),  dim3(256), 0, stream, c1W, film, c1Wt);
  hipLaunchKernelGGL(prep_bias_kernel, dim3(1),   dim3(128), 0, stream, c1b, film, c1W, biasp);
  hipLaunchKernelGGL(prep_P_kernel,    dim3(625), dim3(256), 0, stream, h, wPt, ib, P);
  hipLaunchKernelGGL(copy_pos_kernel,  dim3(469), dim3(256), 0, stream, pos, out);
  hipLaunchKernelGGL(edge_kernel,      dim3(EE / TB), dim3(512), 0, stream,
                     pos, edge_attr, dist, c2W, cn, eidx,
                     P, wadWt, c1Wt, biasp, out);
}